// Round 11
// baseline (123.936 us; speedup 1.0000x reference)
//
#include <hip/hip_runtime.h>
#include <hip/hip_bf16.h>
#include <cstdint>
#include <cstddef>

typedef __bf16 bf16;
typedef __bf16 bf16x2 __attribute__((ext_vector_type(2)));
typedef __bf16 bf16x4 __attribute__((ext_vector_type(4)));
typedef __bf16 bf16x8 __attribute__((ext_vector_type(8)));
typedef float f32x4 __attribute__((ext_vector_type(4)));
typedef float f32x16 __attribute__((ext_vector_type(16)));
typedef unsigned int u32x4 __attribute__((ext_vector_type(4)));

#define S_LEN 2048
#define DM 1024
#define NH 16
#define HD 64
#define NQKV (4096 * 1024)   // tokens * DM
#define NW (1024 * 1024)
// (1/sqrt(64)) * log2(e): fold softmax scale + exp2 conversion into Q
#define QK_SCALE 0.18033688011112042f

__device__ __forceinline__ void gload_lds16(const bf16* g, bf16* l) {
  __builtin_amdgcn_global_load_lds(
      (const __attribute__((address_space(1))) void*)g,
      (__attribute__((address_space(3))) void*)l, 16, 0, 0);
}

__device__ __forceinline__ unsigned packbf(float lo, float hi) {
  bf16x2 t;
  t[0] = (bf16)lo;
  t[1] = (bf16)hi;
  return __builtin_bit_cast(unsigned, t);
}

// v_permlane32_swap_b32: new_a[l>=32] = b_old[l-32]; new_b[l<32] = a_old[l+32]
__device__ __forceinline__ void pl32swap(unsigned& a, unsigned& b) {
#if __has_builtin(__builtin_amdgcn_permlane32_swap)
  auto r = __builtin_amdgcn_permlane32_swap((int)a, (int)b, false, false);
  a = (unsigned)r[0];
  b = (unsigned)r[1];
#else
  asm volatile("v_permlane32_swap_b32 %0, %1" : "+v"(a), "+v"(b));
#endif
}

// ---------------- fused fp32 -> bf16 convert for all 7 tensors ----------------
__global__ __launch_bounds__(256) void cvt_all(
    const float* __restrict__ q, const float* __restrict__ k, const float* __restrict__ v,
    const float* __restrict__ Wq, const float* __restrict__ Wk, const float* __restrict__ Wv,
    const float* __restrict__ Wo, bf16* __restrict__ out) {
  const size_t i = ((size_t)blockIdx.x * 256 + threadIdx.x) * 8;
  const float* src;
  size_t off;
  if (i < (size_t)NQKV) { src = q; off = i; }
  else if (i < 2ull * NQKV) { src = k; off = i - NQKV; }
  else if (i < 3ull * NQKV) { src = v; off = i - 2ull * NQKV; }
  else {
    const size_t j = i - 3ull * NQKV;
    if (j < (size_t)NW) { src = Wq; off = j; }
    else if (j < 2ull * NW) { src = Wk; off = j - NW; }
    else if (j < 3ull * NW) { src = Wv; off = j - 2ull * NW; }
    else { src = Wo; off = j - 3ull * NW; }
  }
  const float4 a = *(const float4*)(src + off);
  const float4 b = *(const float4*)(src + off + 4);
  bf16x8 o;
  o[0] = (bf16)a.x; o[1] = (bf16)a.y; o[2] = (bf16)a.z; o[3] = (bf16)a.w;
  o[4] = (bf16)b.x; o[5] = (bf16)b.y; o[6] = (bf16)b.z; o[7] = (bf16)b.w;
  *(bf16x8*)(out + i) = o;
}

// ---------------- GEMM: Y[m,n] = sum_k A[m,k] * W[n,k] + bias[n] ----------------
// MODE 2: out fp32, row-major [M,N]   (final projection)
// MODE 3: fused QKV; seg = n0>>10: seg0 Q head-major*QK_SCALE, seg1 K head-major,
//         seg2 V per-head transposed [B,H,hd,S] via LDS-transposed epilogue.
template <int MODE>
__global__ __launch_bounds__(256, 2) void gemm_bt(
    const bf16* __restrict__ A, const bf16* __restrict__ W,
    const float* __restrict__ bias0, const float* __restrict__ bias1,
    const float* __restrict__ bias2, void* __restrict__ Out,
    int M, int N, int K, float scale) {
  __shared__ __align__(16) bf16 sm[2 * 128 * 64];
  bf16* Asl = sm;
  bf16* Bsl = sm + 128 * 64;
  const int tid = threadIdx.x;
  const int lane = tid & 63, w = tid >> 6;
  const int wr = w >> 1, wc = w & 1;
  const int r16 = lane & 15, grp = lane >> 4;

  // XCD swizzle: consecutive blocks within an XCD share A-panels
  int flat = blockIdx.y * gridDim.x + blockIdx.x;
  const int cpx = (gridDim.x * gridDim.y) >> 3;
  flat = (flat & 7) * cpx + (flat >> 3);
  const int m0 = (flat / gridDim.x) * 128;
  const int n0 = (flat % gridDim.x) * 128;

  const int seg = n0 >> 10;
  const bf16* Ab = (MODE == 3) ? A + (size_t)seg * NQKV : A;

  f32x4 acc[4][4] = {};

  const int nk = K >> 6;
  for (int t = 0; t < nk; ++t) {
    const int k0 = t << 6;
    __syncthreads();
#pragma unroll
    for (int j = 0; j < 4; ++j) {
      const int lin = j * 256 + tid;
      const int rr = lin >> 3;
      const int cc = (lin & 7) * 8;
      gload_lds16(&Ab[(size_t)(m0 + rr) * K + k0 + cc], &Asl[lin * 8]);
      gload_lds16(&W[(size_t)(n0 + rr) * K + k0 + cc], &Bsl[lin * 8]);
    }
    __syncthreads();
#pragma unroll
    for (int kk = 0; kk < 2; ++kk) {
      bf16x8 af[4], bfr[4];
#pragma unroll
      for (int m = 0; m < 4; ++m)
        af[m] = *(const bf16x8*)&Asl[(wr * 64 + m * 16 + r16) * 64 + kk * 32 + grp * 8];
#pragma unroll
      for (int n = 0; n < 4; ++n)
        bfr[n] = *(const bf16x8*)&Bsl[(wc * 64 + n * 16 + r16) * 64 + kk * 32 + grp * 8];
#pragma unroll
      for (int m = 0; m < 4; ++m)
#pragma unroll
        for (int n = 0; n < 4; ++n)
          acc[m][n] = __builtin_amdgcn_mfma_f32_16x16x32_bf16(af[m], bfr[n], acc[m][n], 0, 0, 0);
    }
  }

  const float* bp = (MODE == 3) ? (seg == 0 ? bias0 : (seg == 1 ? bias1 : bias2)) : bias0;
  const float sc = (MODE == 3) ? (seg == 0 ? scale : 1.0f) : scale;

  if (MODE == 3 && seg == 2) {
    // ---- V^T epilogue: transpose each wave's 64x64 quadrant via LDS ----
    __syncthreads();  // all Asl/Bsl readers done
    bf16* T = sm + w * (32 * 76);
    const int b = (m0 + wr * 64) >> 11;
    const int srow0 = (m0 + wr * 64) & 2047;
    bf16* base2 = (bf16*)Out + 2 * (size_t)NQKV;
#pragma unroll
    for (int p = 0; p < 2; ++p) {
#pragma unroll
      for (int nn = 0; nn < 2; ++nn) {
        const int n = 2 * p + nn;
#pragma unroll
        for (int mq = 0; mq < 4; ++mq)
#pragma unroll
          for (int r = 0; r < 4; ++r) {
            const int d_l = nn * 16 + r16;
            const int s_l = mq * 16 + grp * 4 + r;
            const int cs = (n0 + wc * 64 + n * 16 + r16) & 1023;
            T[d_l * 76 + s_l] = (bf16)(acc[mq][n][r] + bp[cs]);
          }
      }
      __syncthreads();
#pragma unroll
      for (int j = 0; j < 4; ++j) {
        const int d_l = j * 8 + (lane >> 3);
        const int scnk = lane & 7;
        const uint2 lo = *(const uint2*)&T[d_l * 76 + scnk * 8];
        const uint2 hi = *(const uint2*)&T[d_l * 76 + scnk * 8 + 4];
        const int cs = (n0 + wc * 64 + p * 32 + d_l) & 1023;
        const int hh = cs >> 6, dd = cs & 63;
        bf16* dst = base2 + ((size_t)(b * NH + hh) * HD + dd) * S_LEN + srow0 + scnk * 8;
        uint4 val; val.x = lo.x; val.y = lo.y; val.z = hi.x; val.w = hi.y;
        *(uint4*)dst = val;
      }
      __syncthreads();
    }
    return;
  }

#pragma unroll
  for (int m = 0; m < 4; ++m) {
#pragma unroll
    for (int n = 0; n < 4; ++n) {
#pragma unroll
      for (int r = 0; r < 4; ++r) {
        const int row = m0 + wr * 64 + m * 16 + grp * 4 + r;
        const int col = n0 + wc * 64 + n * 16 + r16;
        const int cs = col & 1023;
        const float v = (acc[m][n][r] + bp[cs]) * sc;
        if (MODE == 3) {  // seg 0/1: head-major
          const int b = row >> 11, s = row & 2047, h = cs >> 6, d = cs & 63;
          bf16* base = (bf16*)Out + (size_t)seg * NQKV;
          base[((size_t)(b * NH + h) * S_LEN + s) * HD + d] = (bf16)v;
        } else {
          ((float*)Out)[(size_t)row * N + col] = v;
        }
      }
    }
  }
}

// ------- causal flash attention: paired chunks, key-split waves, 2-tile iters ---
// 512 blocks x 4 waves; block = (bh, chunk pair (c,31-c)) -> 33 staged tiles per
// block (equal work, round-8 proven). Wave (qh,kh) = q-half x key-half; split-K
// combine at chunk end. 2 K-tiles per barrier-iteration: one merged
// tree-max/rescale/sum over 32 scores, one barrier per 128 keys.
// RACE FIX vs r10: 4-slot ring, but STAGE AFTER the barrier (round-8 discipline).
// Slot (t0+2)&3 is read at iter it-1 and overwritten after iter it's barrier ->
// one full barrier separates read from overwrite. vmcnt(0) before the barrier is
// cheap: the loads had an entire 2-tile compute phase (~1400 cyc) to land.
__global__ __launch_bounds__(256, 2) void attn_fwd11(
    const bf16* __restrict__ Qh, const bf16* __restrict__ Kh,
    const bf16* __restrict__ Vt, bf16* __restrict__ AO) {
  __shared__ __align__(16) bf16 Kl[4][64 * 64];
  __shared__ __align__(16) bf16 Vl[4][64 * 64];

  const int tid = threadIdx.x;
  const int lane = tid & 63, w = tid >> 6;
  const int q31 = lane & 31, h = lane >> 5;
  const int qh = w >> 1, kh = w & 1;
  const int koff = kh << 5;

  const int bid = blockIdx.x;
  const int xcd = bid & 7;
  const int within = bid >> 3;           // 0..63
  const int bh = xcd * 4 + (within & 3);
  const int p = within >> 2;             // 0..15

  const bf16* Qb = Qh + (size_t)bh * S_LEN * HD;
  const bf16* Kb = Kh + (size_t)bh * S_LEN * HD;
  const bf16* Vb = Vt + (size_t)bh * HD * S_LEN;

  // staging offsets: 8KB tile = 512 x 16B; 256 threads x 2 issues (K and V)
  int stK[2], stV[2], stL[2];
#pragma unroll
  for (int i = 0; i < 2; ++i) {
    const int lin = i * 256 + tid;       // 0..511
    const int row = lin >> 3;            // 0..63
    const int colb = (lin & 7) * 16;
    const int scol = colb ^ ((row & 7) << 4);
    stK[i] = row * HD + (scol >> 1);
    stV[i] = row * S_LEN + (scol >> 1);
    stL[i] = lin * 8;
  }
  const int swz = (q31 & 7) << 4;

#define STAGE(t, buf)                                                          \
  {                                                                            \
    const bf16* kb_ = Kb + (size_t)(t) * 64 * HD;                              \
    const bf16* vb_ = Vb + (t) * 64;                                           \
    _Pragma("unroll") for (int i = 0; i < 2; ++i) {                            \
      gload_lds16(kb_ + stK[i], &Kl[buf][stL[i]]);                             \
      gload_lds16(vb_ + stV[i], &Vl[buf][stL[i]]);                             \
    }                                                                          \
  }

  auto run_chunk = [&](const int q0, const int nt) {
    const int q0w = q0 + (qh << 5);
    const int qg = q0w + q31;
    const int nt_w = (w == 1) ? nt - 1 : nt;   // w1's key-half never reaches diag
    const bool maskw = (w == 0) || (w == 3);   // triangular waves

    bf16x8 qf[4];
#pragma unroll
    for (int ks = 0; ks < 4; ++ks)
      qf[ks] = *(const bf16x8*)&Qb[(size_t)qg * HD + ks * 16 + 8 * h];

    f32x16 acc0 = {}, acc1 = {};
    float m = -1e30f, l = 0.f;

    // prologue: tiles 0,1 into slots 0,1
    STAGE(0, 0)
    if (nt > 1) STAGE(1, 1)

    const int npair = (nt + 1) >> 1;
    for (int it = 0; it < npair; ++it) {
      const int t0 = it << 1;
      // tiles t0,t0+1 staged one iteration ago -> drain (near-free: loads had a
      // full compute phase to land), barrier, THEN overwrite-stage 2 ahead.
      asm volatile("s_waitcnt vmcnt(0)" ::: "memory");
      __builtin_amdgcn_s_barrier();
      if (t0 + 2 < nt) STAGE(t0 + 2, (t0 + 2) & 3)
      if (t0 + 3 < nt) STAGE(t0 + 3, (t0 + 3) & 3)

      const bool live1 = (t0 + 1 < nt_w);
      if (t0 < nt_w) {
        const char* Kl0 = (const char*)&Kl[t0 & 3][0];
        const char* Vl0 = (const char*)&Vl[t0 & 3][0];
        const char* Kl1 = (const char*)&Kl[(t0 + 1) & 3][0];
        const char* Vl1 = (const char*)&Vl[(t0 + 1) & 3][0];

        // ---- QK^T both tiles ----
        f32x16 s0 = {}, s1 = {};
        {
          bf16x8 kf[4];
#pragma unroll
          for (int ks = 0; ks < 4; ++ks) {
            const int c = (32 * ks + 16 * h) ^ swz;
            kf[ks] = *(const bf16x8*)(Kl0 + (koff + q31) * 128 + c);
          }
          __builtin_amdgcn_s_setprio(1);
#pragma unroll
          for (int ks = 0; ks < 4; ++ks)
            s0 = __builtin_amdgcn_mfma_f32_32x32x16_bf16(kf[ks], qf[ks], s0, 0, 0, 0);
          __builtin_amdgcn_s_setprio(0);
        }
        if (live1) {
          bf16x8 kf[4];
#pragma unroll
          for (int ks = 0; ks < 4; ++ks) {
            const int c = (32 * ks + 16 * h) ^ swz;
            kf[ks] = *(const bf16x8*)(Kl1 + (koff + q31) * 128 + c);
          }
          __builtin_amdgcn_s_setprio(1);
#pragma unroll
          for (int ks = 0; ks < 4; ++ks)
            s1 = __builtin_amdgcn_mfma_f32_32x32x16_bf16(kf[ks], qf[ks], s1, 0, 0, 0);
          __builtin_amdgcn_s_setprio(0);
        }

        // ---- causal masks (diag tile; key row = (r&3)+8*(r>>2)+4h) ----
        if (maskw) {
          if (t0 == nt - 1) {
#pragma unroll
            for (int r = 0; r < 16; ++r) {
              const int key = (t0 << 6) + koff + (r & 3) + 8 * (r >> 2) + 4 * h;
              if (key > qg) s0[r] = -1e30f;
            }
          }
          if (live1 && t0 + 1 == nt - 1) {
#pragma unroll
            for (int r = 0; r < 16; ++r) {
              const int key = ((t0 + 1) << 6) + koff + (r & 3) + 8 * (r >> 2) + 4 * h;
              if (key > qg) s1[r] = -1e30f;
            }
          }
        }

        // ---- merged tree max over both tiles ----
        float t_[16];
        if (live1) {
#pragma unroll
          for (int r = 0; r < 16; ++r) t_[r] = fmaxf(s0[r], s1[r]);
        } else {
#pragma unroll
          for (int r = 0; r < 16; ++r) t_[r] = s0[r];
        }
#pragma unroll
        for (int s = 8; s >= 1; s >>= 1)
#pragma unroll
          for (int r = 0; r < s; ++r) t_[r] = fmaxf(t_[r], t_[r + s]);
        const float pmax = fmaxf(t_[0], __shfl_xor(t_[0], 32));
        // ---- defer-max (T13), once per 128 keys ----
        if (!__all(pmax - m <= 8.0f)) {
          const float mn = fmaxf(m, pmax);
          const float al = exp2f(m - mn);
          m = mn;
          l *= al;
#pragma unroll
          for (int r = 0; r < 16; ++r) { acc0[r] *= al; acc1[r] *= al; }
        }
        // ---- exp + merged tree sum ----
        float sv[16];
#pragma unroll
        for (int r = 0; r < 16; ++r) {
          s0[r] = exp2f(s0[r] - m);
          sv[r] = s0[r];
        }
        if (live1) {
#pragma unroll
          for (int r = 0; r < 16; ++r) {
            s1[r] = exp2f(s1[r] - m);
            sv[r] += s1[r];
          }
        }
#pragma unroll
        for (int s = 8; s >= 1; s >>= 1)
#pragma unroll
          for (int r = 0; r < s; ++r) sv[r] += sv[r + s];
        l += sv[0] + __shfl_xor(sv[0], 32);

        // ---- pack + PV tile 0 ----
        {
          unsigned wv[8];
#pragma unroll
          for (int mm = 0; mm < 8; ++mm)
            wv[mm] = packbf(s0[2 * mm], s0[2 * mm + 1]);
          pl32swap(wv[0], wv[2]);
          pl32swap(wv[1], wv[3]);
          pl32swap(wv[4], wv[6]);
          pl32swap(wv[5], wv[7]);
          bf16x8 vf[4];
#pragma unroll
          for (int ks = 0; ks < 2; ++ks)
#pragma unroll
            for (int db = 0; db < 2; ++db) {
              const int c = (64 * kh + 32 * ks + 16 * h) ^ swz;
              vf[ks * 2 + db] = *(const bf16x8*)(Vl0 + (db * 32 + q31) * 128 + c);
            }
          __builtin_amdgcn_s_setprio(1);
          u32x4 pu0 = {wv[0], wv[1], wv[2], wv[3]};
          const bf16x8 pf0 = __builtin_bit_cast(bf16x8, pu0);
          acc0 = __builtin_amdgcn_mfma_f32_32x32x16_bf16(vf[0], pf0, acc0, 0, 0, 0);
          acc1 = __builtin_amdgcn_mfma_f32_32x32x16_bf16(vf[1], pf0, acc1, 0, 0, 0);
          u32x4 pu1 = {wv[4], wv[5], wv[6], wv[7]};
          const bf16x8 pf1 = __builtin_bit_cast(bf16x8, pu1);
          acc0 = __builtin_amdgcn_mfma_f32_32x32x16_bf16(vf[2], pf1, acc0, 0, 0, 0);
          acc1 = __builtin_amdgcn_mfma_f32_32x32x16_bf16(vf[3], pf1, acc1, 0, 0, 0);
          __builtin_amdgcn_s_setprio(0);
        }
        // ---- pack + PV tile 1 ----
        if (live1) {
          unsigned wv[8];
#pragma unroll
          for (int mm = 0; mm < 8; ++mm)
            wv[mm] = packbf(s1[2 * mm], s1[2 * mm + 1]);
          pl32swap(wv[0], wv[2]);
          pl32swap(wv[1], wv[3]);
          pl32swap(wv[4], wv[6]);
          pl32swap(wv[5], wv[7]);
          bf16x8 vf[4];
#pragma unroll
          for (int ks = 0; ks < 2; ++ks)
#pragma unroll
            for (int db = 0; db < 2; ++db) {
              const int c = (64 * kh + 32 * ks + 16 * h) ^ swz;
              vf[ks * 2 + db] = *(const bf16x8*)(Vl1 + (db * 32 + q31) * 128 + c);
            }
          __builtin_amdgcn_s_setprio(1);
          u32x4 pu0 = {wv[0], wv[1], wv[2], wv[3]};
          const bf16x8 pf0 = __builtin_bit_cast(bf16x8, pu0);
          acc0 = __builtin_amdgcn_mfma_f32_32x32x16_bf16(vf[0], pf0, acc0, 0, 0, 0);
          acc1 = __builtin_amdgcn_mfma_f32_32x32x16_bf16(vf[1], pf0, acc1, 0, 0, 0);
          u32x4 pu1 = {wv[4], wv[5], wv[6], wv[7]};
          const bf16x8 pf1 = __builtin_bit_cast(bf16x8, pu1);
          acc0 = __builtin_amdgcn_mfma_f32_32x32x16_bf16(vf[2], pf1, acc0, 0, 0, 0);
          acc1 = __builtin_amdgcn_mfma_f32_32x32x16_bf16(vf[3], pf1, acc1, 0, 0, 0);
          __builtin_amdgcn_s_setprio(0);
        }
      }
    }

    // ---- split-K combine across key-half waves (scratch over Kl; pitch 34) ----
    float* scr = (float*)&Kl[0][0];
    float* s = scr + (size_t)qh * (64 * 34) + lane * 34;
    __syncthreads();  // drains vmcnt+lgkmcnt; all ring reads done
    if (kh) {
#pragma unroll
      for (int r = 0; r < 16; ++r) { s[r] = acc0[r]; s[16 + r] = acc1[r]; }
      s[32] = m;
      s[33] = l;
    }
    __syncthreads();
    if (!kh) {
      const float m1 = s[32], l1 = s[33];
      const float mn = fmaxf(m, m1);
      const float a0 = exp2f(m - mn), a1 = exp2f(m1 - mn);
      const float linv = 1.0f / (a0 * l + a1 * l1);
      const int b = bh >> 4, hh = bh & 15;
      bf16* orow = AO + ((size_t)(b * S_LEN + qg)) * DM + hh * HD;
#pragma unroll
      for (int mm = 0; mm < 4; ++mm) {
        bf16x4 ov0, ov1;
#pragma unroll
        for (int t2 = 0; t2 < 4; ++t2) {
          ov0[t2] = (bf16)((a0 * acc0[4 * mm + t2] + a1 * s[4 * mm + t2]) * linv);
          ov1[t2] = (bf16)((a0 * acc1[4 * mm + t2] + a1 * s[16 + 4 * mm + t2]) * linv);
        }
        *(bf16x4*)&orow[8 * mm + 4 * h] = ov0;
        *(bf16x4*)&orow[32 + 8 * mm + 4 * h] = ov1;
      }
    }
    __syncthreads();  // scratch reads done before next phase's staging
  };

  // phase A: light chunk p (p+1 tiles); phase B: heavy chunk 31-p (32-p tiles)
  run_chunk(p << 6, p + 1);
  run_chunk((31 - p) << 6, 32 - p);
#undef STAGE
}

// ---------------- launch ----------------
extern "C" void kernel_launch(void* const* d_in, const int* in_sizes, int n_in,
                              void* d_out, int out_size, void* d_ws, size_t ws_size,
                              hipStream_t stream) {
  const float* q  = (const float*)d_in[0];
  const float* k  = (const float*)d_in[1];
  const float* v  = (const float*)d_in[2];
  const float* Wq = (const float*)d_in[3];
  const float* bq = (const float*)d_in[4];
  const float* Wk = (const float*)d_in[5];
  const float* bk = (const float*)d_in[6];
  const float* Wv = (const float*)d_in[7];
  const float* bv = (const float*)d_in[8];
  const float* Wo = (const float*)d_in[9];
  const float* bo = (const float*)d_in[10];

  const int NTOK = 2 * S_LEN;          // 4096

  bf16* qb  = (bf16*)d_ws;             // q,k,v bf16: 3 * NQKV (consecutive)
  bf16* Wqb = qb + 3 * (size_t)NQKV;   // Wq,Wk,Wv,Wo bf16: 4 * NW (consecutive)
  bf16* Wob = Wqb + 3 * (size_t)NW;
  bf16* Qh  = Wqb + 4 * (size_t)NW;    // Qh,Kh,Vt bf16: 3 * NQKV (consecutive)
  bf16* Kh  = Qh + (size_t)NQKV;
  bf16* Vt  = Kh + (size_t)NQKV;
  bf16* AO  = Vt + (size_t)NQKV;

  const int cvt_blocks = (3 * NQKV + 4 * NW) / 8 / 256;
  cvt_all<<<cvt_blocks, 256, 0, stream>>>(q, k, v, Wq, Wk, Wv, Wo, qb);

  // fused QKV projection: M=4096, N=3072, K=1024
  gemm_bt<3><<<dim3(3 * DM / 128, NTOK / 128), 256, 0, stream>>>(
      qb, Wqb, bq, bk, bv, Qh, NTOK, 3 * DM, DM, QK_SCALE);

  // attention: 512 equal-work blocks x 256 threads, 2-tile merged iterations
  attn_fwd11<<<dim3(512), 256, 0, stream>>>(Qh, Kh, Vt, AO);

  // output projection -> fp32 d_out
  gemm_bt<2><<<dim3(DM / 128, NTOK / 128), 256, 0, stream>>>(
      AO, Wob, bo, bo, bo, d_out, NTOK, DM, DM, 1.0f);
}

// Round 12
// 120.688 us; speedup vs baseline: 1.0269x; 1.0269x over previous
//
#include <hip/hip_runtime.h>
#include <hip/hip_bf16.h>
#include <cstdint>
#include <cstddef>

typedef __bf16 bf16;
typedef __bf16 bf16x2 __attribute__((ext_vector_type(2)));
typedef __bf16 bf16x4 __attribute__((ext_vector_type(4)));
typedef __bf16 bf16x8 __attribute__((ext_vector_type(8)));
typedef float f32x4 __attribute__((ext_vector_type(4)));
typedef float f32x16 __attribute__((ext_vector_type(16)));
typedef unsigned int u32x4 __attribute__((ext_vector_type(4)));

#define S_LEN 2048
#define DM 1024
#define NH 16
#define HD 64
#define NQKV (4096 * 1024)   // tokens * DM
#define NW (1024 * 1024)
// (1/sqrt(64)) * log2(e): fold softmax scale + exp2 conversion into Q
#define QK_SCALE 0.18033688011112042f

__device__ __forceinline__ void gload_lds16(const bf16* g, bf16* l) {
  __builtin_amdgcn_global_load_lds(
      (const __attribute__((address_space(1))) void*)g,
      (__attribute__((address_space(3))) void*)l, 16, 0, 0);
}

__device__ __forceinline__ unsigned packbf(float lo, float hi) {
  bf16x2 t;
  t[0] = (bf16)lo;
  t[1] = (bf16)hi;
  return __builtin_bit_cast(unsigned, t);
}

// v_permlane32_swap_b32: new_a[l>=32] = b_old[l-32]; new_b[l<32] = a_old[l+32]
__device__ __forceinline__ void pl32swap(unsigned& a, unsigned& b) {
#if __has_builtin(__builtin_amdgcn_permlane32_swap)
  auto r = __builtin_amdgcn_permlane32_swap((int)a, (int)b, false, false);
  a = (unsigned)r[0];
  b = (unsigned)r[1];
#else
  asm volatile("v_permlane32_swap_b32 %0, %1" : "+v"(a), "+v"(b));
#endif
}

// ---------------- fused fp32 -> bf16 convert for all 7 tensors ----------------
__global__ __launch_bounds__(256) void cvt_all(
    const float* __restrict__ q, const float* __restrict__ k, const float* __restrict__ v,
    const float* __restrict__ Wq, const float* __restrict__ Wk, const float* __restrict__ Wv,
    const float* __restrict__ Wo, bf16* __restrict__ out) {
  const size_t i = ((size_t)blockIdx.x * 256 + threadIdx.x) * 8;
  const float* src;
  size_t off;
  if (i < (size_t)NQKV) { src = q; off = i; }
  else if (i < 2ull * NQKV) { src = k; off = i - NQKV; }
  else if (i < 3ull * NQKV) { src = v; off = i - 2ull * NQKV; }
  else {
    const size_t j = i - 3ull * NQKV;
    if (j < (size_t)NW) { src = Wq; off = j; }
    else if (j < 2ull * NW) { src = Wk; off = j - NW; }
    else if (j < 3ull * NW) { src = Wv; off = j - 2ull * NW; }
    else { src = Wo; off = j - 3ull * NW; }
  }
  const float4 a = *(const float4*)(src + off);
  const float4 b = *(const float4*)(src + off + 4);
  bf16x8 o;
  o[0] = (bf16)a.x; o[1] = (bf16)a.y; o[2] = (bf16)a.z; o[3] = (bf16)a.w;
  o[4] = (bf16)b.x; o[5] = (bf16)b.y; o[6] = (bf16)b.z; o[7] = (bf16)b.w;
  *(bf16x8*)(out + i) = o;
}

// ---------------- GEMM: Y[m,n] = sum_k A[m,k] * W[n,k] + bias[n] ----------------
// MODE 2: out fp32, row-major [M,N]   (final projection)
// MODE 3: fused QKV; seg = n0>>10: seg0 Q head-major*QK_SCALE, seg1 K head-major,
//         seg2 V per-head transposed [B,H,hd,S] via LDS-transposed epilogue.
// __launch_bounds__(256,3): cap VGPR ~170 so 3 blocks/CU co-reside -> the full
// 768-block QKV grid is resident at once (no 256-block tail epoch) and the
// extra block hides the staging barrier drain (m114 mechanism).
template <int MODE>
__global__ __launch_bounds__(256, 3) void gemm_bt(
    const bf16* __restrict__ A, const bf16* __restrict__ W,
    const float* __restrict__ bias0, const float* __restrict__ bias1,
    const float* __restrict__ bias2, void* __restrict__ Out,
    int M, int N, int K, float scale) {
  __shared__ __align__(16) bf16 sm[2 * 128 * 64];
  bf16* Asl = sm;
  bf16* Bsl = sm + 128 * 64;
  const int tid = threadIdx.x;
  const int lane = tid & 63, w = tid >> 6;
  const int wr = w >> 1, wc = w & 1;
  const int r16 = lane & 15, grp = lane >> 4;

  // XCD swizzle: consecutive blocks within an XCD share A-panels
  int flat = blockIdx.y * gridDim.x + blockIdx.x;
  const int cpx = (gridDim.x * gridDim.y) >> 3;
  flat = (flat & 7) * cpx + (flat >> 3);
  const int m0 = (flat / gridDim.x) * 128;
  const int n0 = (flat % gridDim.x) * 128;

  const int seg = n0 >> 10;
  const bf16* Ab = (MODE == 3) ? A + (size_t)seg * NQKV : A;

  f32x4 acc[4][4] = {};

  const int nk = K >> 6;
  for (int t = 0; t < nk; ++t) {
    const int k0 = t << 6;
    __syncthreads();
#pragma unroll
    for (int j = 0; j < 4; ++j) {
      const int lin = j * 256 + tid;
      const int rr = lin >> 3;
      const int cc = (lin & 7) * 8;
      gload_lds16(&Ab[(size_t)(m0 + rr) * K + k0 + cc], &Asl[lin * 8]);
      gload_lds16(&W[(size_t)(n0 + rr) * K + k0 + cc], &Bsl[lin * 8]);
    }
    __syncthreads();
#pragma unroll
    for (int kk = 0; kk < 2; ++kk) {
      bf16x8 af[4], bfr[4];
#pragma unroll
      for (int m = 0; m < 4; ++m)
        af[m] = *(const bf16x8*)&Asl[(wr * 64 + m * 16 + r16) * 64 + kk * 32 + grp * 8];
#pragma unroll
      for (int n = 0; n < 4; ++n)
        bfr[n] = *(const bf16x8*)&Bsl[(wc * 64 + n * 16 + r16) * 64 + kk * 32 + grp * 8];
#pragma unroll
      for (int m = 0; m < 4; ++m)
#pragma unroll
        for (int n = 0; n < 4; ++n)
          acc[m][n] = __builtin_amdgcn_mfma_f32_16x16x32_bf16(af[m], bfr[n], acc[m][n], 0, 0, 0);
    }
  }

  const float* bp = (MODE == 3) ? (seg == 0 ? bias0 : (seg == 1 ? bias1 : bias2)) : bias0;
  const float sc = (MODE == 3) ? (seg == 0 ? scale : 1.0f) : scale;

  if (MODE == 3 && seg == 2) {
    // ---- V^T epilogue: transpose each wave's 64x64 quadrant via LDS ----
    __syncthreads();  // all Asl/Bsl readers done
    bf16* T = sm + w * (32 * 76);
    const int b = (m0 + wr * 64) >> 11;
    const int srow0 = (m0 + wr * 64) & 2047;
    bf16* base2 = (bf16*)Out + 2 * (size_t)NQKV;
#pragma unroll
    for (int p = 0; p < 2; ++p) {
#pragma unroll
      for (int nn = 0; nn < 2; ++nn) {
        const int n = 2 * p + nn;
#pragma unroll
        for (int mq = 0; mq < 4; ++mq)
#pragma unroll
          for (int r = 0; r < 4; ++r) {
            const int d_l = nn * 16 + r16;
            const int s_l = mq * 16 + grp * 4 + r;
            const int cs = (n0 + wc * 64 + n * 16 + r16) & 1023;
            T[d_l * 76 + s_l] = (bf16)(acc[mq][n][r] + bp[cs]);
          }
      }
      __syncthreads();
#pragma unroll
      for (int j = 0; j < 4; ++j) {
        const int d_l = j * 8 + (lane >> 3);
        const int scnk = lane & 7;
        const uint2 lo = *(const uint2*)&T[d_l * 76 + scnk * 8];
        const uint2 hi = *(const uint2*)&T[d_l * 76 + scnk * 8 + 4];
        const int cs = (n0 + wc * 64 + p * 32 + d_l) & 1023;
        const int hh = cs >> 6, dd = cs & 63;
        bf16* dst = base2 + ((size_t)(b * NH + hh) * HD + dd) * S_LEN + srow0 + scnk * 8;
        uint4 val; val.x = lo.x; val.y = lo.y; val.z = hi.x; val.w = hi.y;
        *(uint4*)dst = val;
      }
      __syncthreads();
    }
    return;
  }

#pragma unroll
  for (int m = 0; m < 4; ++m) {
#pragma unroll
    for (int n = 0; n < 4; ++n) {
#pragma unroll
      for (int r = 0; r < 4; ++r) {
        const int row = m0 + wr * 64 + m * 16 + grp * 4 + r;
        const int col = n0 + wc * 64 + n * 16 + r16;
        const int cs = col & 1023;
        const float v = (acc[m][n][r] + bp[cs]) * sc;
        if (MODE == 3) {  // seg 0/1: head-major
          const int b = row >> 11, s = row & 2047, h = cs >> 6, d = cs & 63;
          bf16* base = (bf16*)Out + (size_t)seg * NQKV;
          base[((size_t)(b * NH + h) * S_LEN + s) * HD + d] = (bf16)v;
        } else {
          ((float*)Out)[(size_t)row * N + col] = v;
        }
      }
    }
  }
}

// ---------------- causal flash attention: paired chunks, key-split waves --------
// (round-8 structure, the measured best: 51.4 us, Occ 17.3%)
// 512 blocks x 4 waves. Block = (bh, chunk pair (c, 31-c) of 64 q-rows each),
// processed in two sequential phases -> EVERY block stages exactly 33 tiles.
// Wave (qh,kh) = q-half x key-half of each 64-key tile; per q-half the two
// key-half waves keep independent online-softmax states, merged once per phase
// via LDS (split-K flash combine). 3-buffer LDS ring, counted vmcnt(4) (T4):
// stage(kt+2) issued after the barrier; at iter kt wait vmcnt(4) so tile kt is
// landed while kt+1's stage stays in flight. XOR-swizzled staging (rule #21).
// QK^T swapped mfma(K,Q), PV swapped mfma(Vt,P): softmax state lane-local.
__global__ __launch_bounds__(256, 2) void attn_fwd8(
    const bf16* __restrict__ Qh, const bf16* __restrict__ Kh,
    const bf16* __restrict__ Vt, bf16* __restrict__ AO) {
  __shared__ __align__(16) bf16 Kl[3][64 * 64];
  __shared__ __align__(16) bf16 Vl[3][64 * 64];

  const int tid = threadIdx.x;
  const int lane = tid & 63, w = tid >> 6;
  const int q31 = lane & 31, h = lane >> 5;
  const int qh = w >> 1, kh = w & 1;
  const int koff = kh << 5;

  // 512 blocks: xcd = bid&7 (4 heads/XCD); p = chunk-pair index 0..15.
  const int bid = blockIdx.x;
  const int xcd = bid & 7;
  const int within = bid >> 3;           // 0..63
  const int bh = xcd * 4 + (within & 3);
  const int p = within >> 2;             // 0..15

  const bf16* Qb = Qh + (size_t)bh * S_LEN * HD;
  const bf16* Kb = Kh + (size_t)bh * S_LEN * HD;
  const bf16* Vb = Vt + (size_t)bh * HD * S_LEN;

  // staging offsets: 8KB tile = 512 x 16B; 256 threads x 2 issues (K and V)
  int stK[2], stV[2], stL[2];
#pragma unroll
  for (int i = 0; i < 2; ++i) {
    const int lin = i * 256 + tid;       // 0..511
    const int row = lin >> 3;            // 0..63
    const int colb = (lin & 7) * 16;
    const int scol = colb ^ ((row & 7) << 4);
    stK[i] = row * HD + (scol >> 1);
    stV[i] = row * S_LEN + (scol >> 1);
    stL[i] = lin * 8;
  }
  const int swz = (q31 & 7) << 4;

#define STAGE(t, buf)                                                          \
  {                                                                            \
    const bf16* kb_ = Kb + (size_t)(t) * 64 * HD;                              \
    const bf16* vb_ = Vb + (t) * 64;                                           \
    _Pragma("unroll") for (int i = 0; i < 2; ++i) {                            \
      gload_lds16(kb_ + stK[i], &Kl[buf][stL[i]]);                             \
      gload_lds16(vb_ + stV[i], &Vl[buf][stL[i]]);                             \
    }                                                                          \
  }

  auto run_chunk = [&](const int q0, const int nt) {
    const int q0w = q0 + (qh << 5);
    const int qg = q0w + q31;
    const int nt_w = (w == 1) ? nt - 1 : nt;   // w1's key-half never reaches diag
    const bool maskw = (w == 0) || (w == 3);   // triangular waves

    bf16x8 qf[4];
#pragma unroll
    for (int ks = 0; ks < 4; ++ks)
      qf[ks] = *(const bf16x8*)&Qb[(size_t)qg * HD + ks * 16 + 8 * h];

    f32x16 acc0 = {}, acc1 = {};
    float m = -1e30f, l = 0.f;

    // prologue: tiles 0,1 into buffers 0,1
    STAGE(0, 0)
    if (nt > 1) STAGE(1, 1)

    int cur = 0;
    for (int kt = 0; kt < nt; ++kt) {
      // tile kt landed when only tile kt+1's 4 stage-instrs are outstanding
      if (kt + 1 < nt) asm volatile("s_waitcnt vmcnt(4)" ::: "memory");
      else             asm volatile("s_waitcnt vmcnt(0)" ::: "memory");
      __builtin_amdgcn_s_barrier();

      if (kt + 2 < nt) {
        int nxt = cur + 2; if (nxt >= 3) nxt -= 3;
        STAGE(kt + 2, nxt)
      }

      if (kt < nt_w) {
        const bf16* KlC = &Kl[cur][0];
        const bf16* VlC = &Vl[cur][0];

        // K A-frags: 32 keys at koff (row = koff+q31; (koff+q31)&7 == q31&7)
        bf16x8 kf[4];
#pragma unroll
        for (int ks = 0; ks < 4; ++ks) {
          const int c = (32 * ks + 16 * h) ^ swz;
          kf[ks] = *(const bf16x8*)((const char*)KlC + (koff + q31) * 128 + c);
        }

        // ---- QK^T (32q x 32k x 64d = 4 mfma) ----
        f32x16 p0 = {};
        __builtin_amdgcn_s_setprio(1);
#pragma unroll
        for (int ks = 0; ks < 4; ++ks)
          p0 = __builtin_amdgcn_mfma_f32_32x32x16_bf16(kf[ks], qf[ks], p0, 0, 0, 0);
        __builtin_amdgcn_s_setprio(0);

        // V A-frags (rows d, cols = wave's 32-key half)
        bf16x8 vf[4];
#pragma unroll
        for (int ks = 0; ks < 2; ++ks)
#pragma unroll
          for (int db = 0; db < 2; ++db) {
            const int c = (64 * kh + 32 * ks + 16 * h) ^ swz;
            vf[ks * 2 + db] =
                *(const bf16x8*)((const char*)VlC + (db * 32 + q31) * 128 + c);
          }

        // ---- causal mask (diag tile, triangular waves only) ----
        if (maskw && kt == nt - 1) {
#pragma unroll
          for (int r = 0; r < 16; ++r) {
            const int key = (kt << 6) + koff + (r & 3) + 8 * (r >> 2) + 4 * h;
            if (key > qg) p0[r] = -1e30f;
          }
        }
        // ---- tree max over 16 + cross-half shuffle ----
        float t_[16];
#pragma unroll
        for (int r = 0; r < 16; ++r) t_[r] = p0[r];
#pragma unroll
        for (int s = 8; s >= 1; s >>= 1)
#pragma unroll
          for (int r = 0; r < s; ++r) t_[r] = fmaxf(t_[r], t_[r + s]);
        const float pmax = fmaxf(t_[0], __shfl_xor(t_[0], 32));
        // ---- defer-max (T13) ----
        if (!__all(pmax - m <= 8.0f)) {
          const float mn = fmaxf(m, pmax);
          const float al = exp2f(m - mn);
          m = mn;
          l *= al;
#pragma unroll
          for (int r = 0; r < 16; ++r) { acc0[r] *= al; acc1[r] *= al; }
        }
        // ---- exp + tree sum ----
        float sv[16];
#pragma unroll
        for (int r = 0; r < 16; ++r) {
          p0[r] = exp2f(p0[r] - m);
          sv[r] = p0[r];
        }
#pragma unroll
        for (int s = 8; s >= 1; s >>= 1)
#pragma unroll
          for (int r = 0; r < s; ++r) sv[r] += sv[r + s];
        l += sv[0] + __shfl_xor(sv[0], 32);

        // ---- pack P -> 2 PV B-frags via permlane32_swap ----
        unsigned wv[8];
#pragma unroll
        for (int mm = 0; mm < 8; ++mm)
          wv[mm] = packbf(p0[2 * mm], p0[2 * mm + 1]);
        pl32swap(wv[0], wv[2]);
        pl32swap(wv[1], wv[3]);
        pl32swap(wv[4], wv[6]);
        pl32swap(wv[5], wv[7]);

        // ---- PV (2 k-steps x 2 d-halves) ----
        __builtin_amdgcn_s_setprio(1);
        {
          u32x4 pu0 = {wv[0], wv[1], wv[2], wv[3]};
          const bf16x8 pf0 = __builtin_bit_cast(bf16x8, pu0);
          acc0 = __builtin_amdgcn_mfma_f32_32x32x16_bf16(vf[0], pf0, acc0, 0, 0, 0);
          acc1 = __builtin_amdgcn_mfma_f32_32x32x16_bf16(vf[1], pf0, acc1, 0, 0, 0);
          u32x4 pu1 = {wv[4], wv[5], wv[6], wv[7]};
          const bf16x8 pf1 = __builtin_bit_cast(bf16x8, pu1);
          acc0 = __builtin_amdgcn_mfma_f32_32x32x16_bf16(vf[2], pf1, acc0, 0, 0, 0);
          acc1 = __builtin_amdgcn_mfma_f32_32x32x16_bf16(vf[3], pf1, acc1, 0, 0, 0);
        }
        __builtin_amdgcn_s_setprio(0);
      }

      ++cur; if (cur == 3) cur = 0;
    }

    // ---- split-K combine across key-half waves (scratch = Kl area) ----
    float* scr = (float*)&Kl[0][0];
    float* s = scr + (size_t)qh * (64 * 34) + lane * 34;
    __syncthreads();  // all reads of ring done; safe to reuse as scratch
    if (kh) {
#pragma unroll
      for (int r = 0; r < 16; ++r) { s[r] = acc0[r]; s[16 + r] = acc1[r]; }
      s[32] = m;
      s[33] = l;
    }
    __syncthreads();
    if (!kh) {
      const float m1 = s[32], l1 = s[33];
      const float mn = fmaxf(m, m1);
      const float a0 = exp2f(m - mn), a1 = exp2f(m1 - mn);
      const float linv = 1.0f / (a0 * l + a1 * l1);
      const int b = bh >> 4, hh = bh & 15;
      bf16* orow = AO + ((size_t)(b * S_LEN + qg)) * DM + hh * HD;
#pragma unroll
      for (int mm = 0; mm < 4; ++mm) {
        bf16x4 ov0, ov1;
#pragma unroll
        for (int t2 = 0; t2 < 4; ++t2) {
          ov0[t2] = (bf16)((a0 * acc0[4 * mm + t2] + a1 * s[4 * mm + t2]) * linv);
          ov1[t2] = (bf16)((a0 * acc1[4 * mm + t2] + a1 * s[16 + 4 * mm + t2]) * linv);
        }
        *(bf16x4*)&orow[8 * mm + 4 * h] = ov0;
        *(bf16x4*)&orow[32 + 8 * mm + 4 * h] = ov1;
      }
    }
    __syncthreads();  // scratch reads done before next phase's staging
  };

  // phase A: light chunk p (p+1 tiles); phase B: heavy chunk 31-p (32-p tiles)
  run_chunk(p << 6, p + 1);
  run_chunk((31 - p) << 6, 32 - p);
#undef STAGE
}

// ---------------- launch ----------------
extern "C" void kernel_launch(void* const* d_in, const int* in_sizes, int n_in,
                              void* d_out, int out_size, void* d_ws, size_t ws_size,
                              hipStream_t stream) {
  const float* q  = (const float*)d_in[0];
  const float* k  = (const float*)d_in[1];
  const float* v  = (const float*)d_in[2];
  const float* Wq = (const float*)d_in[3];
  const float* bq = (const float*)d_in[4];
  const float* Wk = (const float*)d_in[5];
  const float* bk = (const float*)d_in[6];
  const float* Wv = (const float*)d_in[7];
  const float* bv = (const float*)d_in[8];
  const float* Wo = (const float*)d_in[9];
  const float* bo = (const float*)d_in[10];

  const int NTOK = 2 * S_LEN;          // 4096

  bf16* qb  = (bf16*)d_ws;             // q,k,v bf16: 3 * NQKV (consecutive)
  bf16* Wqb = qb + 3 * (size_t)NQKV;   // Wq,Wk,Wv,Wo bf16: 4 * NW (consecutive)
  bf16* Wob = Wqb + 3 * (size_t)NW;
  bf16* Qh  = Wqb + 4 * (size_t)NW;    // Qh,Kh,Vt bf16: 3 * NQKV (consecutive)
  bf16* Kh  = Qh + (size_t)NQKV;
  bf16* Vt  = Kh + (size_t)NQKV;
  bf16* AO  = Vt + (size_t)NQKV;

  const int cvt_blocks = (3 * NQKV + 4 * NW) / 8 / 256;
  cvt_all<<<cvt_blocks, 256, 0, stream>>>(q, k, v, Wq, Wk, Wv, Wo, qb);

  // fused QKV projection: M=4096, N=3072, K=1024
  gemm_bt<3><<<dim3(3 * DM / 128, NTOK / 128), 256, 0, stream>>>(
      qb, Wqb, bq, bk, bv, Qh, NTOK, 3 * DM, DM, QK_SCALE);

  // attention: 512 equal-work blocks x 256 threads (round-8 structure)
  attn_fwd8<<<dim3(512), 256, 0, stream>>>(Qh, Kh, Vt, AO);

  // output projection -> fp32 d_out
  gemm_bt<2><<<dim3(DM / 128, NTOK / 128), 256, 0, stream>>>(
      AO, Wob, bo, bo, bo, d_out, NTOK, DM, DM, 1.0f);
}

// Round 13
// 115.988 us; speedup vs baseline: 1.0685x; 1.0405x over previous
//
#include <hip/hip_runtime.h>
#include <hip/hip_bf16.h>
#include <cstdint>
#include <cstddef>

typedef __bf16 bf16;
typedef __bf16 bf16x2 __attribute__((ext_vector_type(2)));
typedef __bf16 bf16x4 __attribute__((ext_vector_type(4)));
typedef __bf16 bf16x8 __attribute__((ext_vector_type(8)));
typedef float f32x4 __attribute__((ext_vector_type(4)));
typedef float f32x16 __attribute__((ext_vector_type(16)));
typedef unsigned int u32x4 __attribute__((ext_vector_type(4)));

#define S_LEN 2048
#define DM 1024
#define NH 16
#define HD 64
#define NQKV (4096 * 1024)   // tokens * DM
#define NW (1024 * 1024)
// (1/sqrt(64)) * log2(e): fold softmax scale + exp2 conversion into Q
#define QK_SCALE 0.18033688011112042f

__device__ __forceinline__ void gload_lds16(const bf16* g, bf16* l) {
  __builtin_amdgcn_global_load_lds(
      (const __attribute__((address_space(1))) void*)g,
      (__attribute__((address_space(3))) void*)l, 16, 0, 0);
}

__device__ __forceinline__ unsigned packbf(float lo, float hi) {
  bf16x2 t;
  t[0] = (bf16)lo;
  t[1] = (bf16)hi;
  return __builtin_bit_cast(unsigned, t);
}

// v_permlane32_swap_b32: new_a[l>=32] = b_old[l-32]; new_b[l<32] = a_old[l+32]
__device__ __forceinline__ void pl32swap(unsigned& a, unsigned& b) {
#if __has_builtin(__builtin_amdgcn_permlane32_swap)
  auto r = __builtin_amdgcn_permlane32_swap((int)a, (int)b, false, false);
  a = (unsigned)r[0];
  b = (unsigned)r[1];
#else
  asm volatile("v_permlane32_swap_b32 %0, %1" : "+v"(a), "+v"(b));
#endif
}

// ---------------- fused fp32 -> bf16 convert for all 7 tensors ----------------
__global__ __launch_bounds__(256) void cvt_all(
    const float* __restrict__ q, const float* __restrict__ k, const float* __restrict__ v,
    const float* __restrict__ Wq, const float* __restrict__ Wk, const float* __restrict__ Wv,
    const float* __restrict__ Wo, bf16* __restrict__ out) {
  const size_t i = ((size_t)blockIdx.x * 256 + threadIdx.x) * 8;
  const float* src;
  size_t off;
  if (i < (size_t)NQKV) { src = q; off = i; }
  else if (i < 2ull * NQKV) { src = k; off = i - NQKV; }
  else if (i < 3ull * NQKV) { src = v; off = i - 2ull * NQKV; }
  else {
    const size_t j = i - 3ull * NQKV;
    if (j < (size_t)NW) { src = Wq; off = j; }
    else if (j < 2ull * NW) { src = Wk; off = j - NW; }
    else if (j < 3ull * NW) { src = Wv; off = j - 2ull * NW; }
    else { src = Wo; off = j - 3ull * NW; }
  }
  const float4 a = *(const float4*)(src + off);
  const float4 b = *(const float4*)(src + off + 4);
  bf16x8 o;
  o[0] = (bf16)a.x; o[1] = (bf16)a.y; o[2] = (bf16)a.z; o[3] = (bf16)a.w;
  o[4] = (bf16)b.x; o[5] = (bf16)b.y; o[6] = (bf16)b.z; o[7] = (bf16)b.w;
  *(bf16x8*)(out + i) = o;
}

// ---------------- GEMM: Y[m,n] = sum_k A[m,k] * W[n,k] + bias[n] ----------------
// MODE 2: out fp32, row-major [M,N]   (final projection)
// MODE 3: fused QKV; seg = n0>>10: seg0 Q head-major*QK_SCALE, seg1 K head-major,
//         seg2 V per-head transposed [B,H,hd,S] via LDS-transposed epilogue.
template <int MODE>
__global__ __launch_bounds__(256, 3) void gemm_bt(
    const bf16* __restrict__ A, const bf16* __restrict__ W,
    const float* __restrict__ bias0, const float* __restrict__ bias1,
    const float* __restrict__ bias2, void* __restrict__ Out,
    int M, int N, int K, float scale) {
  __shared__ __align__(16) bf16 sm[2 * 128 * 64];
  bf16* Asl = sm;
  bf16* Bsl = sm + 128 * 64;
  const int tid = threadIdx.x;
  const int lane = tid & 63, w = tid >> 6;
  const int wr = w >> 1, wc = w & 1;
  const int r16 = lane & 15, grp = lane >> 4;

  // XCD swizzle: consecutive blocks within an XCD share A-panels
  int flat = blockIdx.y * gridDim.x + blockIdx.x;
  const int cpx = (gridDim.x * gridDim.y) >> 3;
  flat = (flat & 7) * cpx + (flat >> 3);
  const int m0 = (flat / gridDim.x) * 128;
  const int n0 = (flat % gridDim.x) * 128;

  const int seg = n0 >> 10;
  const bf16* Ab = (MODE == 3) ? A + (size_t)seg * NQKV : A;

  f32x4 acc[4][4] = {};

  const int nk = K >> 6;
  for (int t = 0; t < nk; ++t) {
    const int k0 = t << 6;
    __syncthreads();
#pragma unroll
    for (int j = 0; j < 4; ++j) {
      const int lin = j * 256 + tid;
      const int rr = lin >> 3;
      const int cc = (lin & 7) * 8;
      gload_lds16(&Ab[(size_t)(m0 + rr) * K + k0 + cc], &Asl[lin * 8]);
      gload_lds16(&W[(size_t)(n0 + rr) * K + k0 + cc], &Bsl[lin * 8]);
    }
    __syncthreads();
#pragma unroll
    for (int kk = 0; kk < 2; ++kk) {
      bf16x8 af[4], bfr[4];
#pragma unroll
      for (int m = 0; m < 4; ++m)
        af[m] = *(const bf16x8*)&Asl[(wr * 64 + m * 16 + r16) * 64 + kk * 32 + grp * 8];
#pragma unroll
      for (int n = 0; n < 4; ++n)
        bfr[n] = *(const bf16x8*)&Bsl[(wc * 64 + n * 16 + r16) * 64 + kk * 32 + grp * 8];
#pragma unroll
      for (int m = 0; m < 4; ++m)
#pragma unroll
        for (int n = 0; n < 4; ++n)
          acc[m][n] = __builtin_amdgcn_mfma_f32_16x16x32_bf16(af[m], bfr[n], acc[m][n], 0, 0, 0);
    }
  }

  const float* bp = (MODE == 3) ? (seg == 0 ? bias0 : (seg == 1 ? bias1 : bias2)) : bias0;
  const float sc = (MODE == 3) ? (seg == 0 ? scale : 1.0f) : scale;

  if (MODE == 3 && seg == 2) {
    // ---- V^T epilogue: transpose each wave's 64x64 quadrant via LDS ----
    __syncthreads();  // all Asl/Bsl readers done
    bf16* T = sm + w * (32 * 76);
    const int b = (m0 + wr * 64) >> 11;
    const int srow0 = (m0 + wr * 64) & 2047;
    bf16* base2 = (bf16*)Out + 2 * (size_t)NQKV;
#pragma unroll
    for (int p = 0; p < 2; ++p) {
#pragma unroll
      for (int nn = 0; nn < 2; ++nn) {
        const int n = 2 * p + nn;
#pragma unroll
        for (int mq = 0; mq < 4; ++mq)
#pragma unroll
          for (int r = 0; r < 4; ++r) {
            const int d_l = nn * 16 + r16;
            const int s_l = mq * 16 + grp * 4 + r;
            const int cs = (n0 + wc * 64 + n * 16 + r16) & 1023;
            T[d_l * 76 + s_l] = (bf16)(acc[mq][n][r] + bp[cs]);
          }
      }
      __syncthreads();
#pragma unroll
      for (int j = 0; j < 4; ++j) {
        const int d_l = j * 8 + (lane >> 3);
        const int scnk = lane & 7;
        const uint2 lo = *(const uint2*)&T[d_l * 76 + scnk * 8];
        const uint2 hi = *(const uint2*)&T[d_l * 76 + scnk * 8 + 4];
        const int cs = (n0 + wc * 64 + p * 32 + d_l) & 1023;
        const int hh = cs >> 6, dd = cs & 63;
        bf16* dst = base2 + ((size_t)(b * NH + hh) * HD + dd) * S_LEN + srow0 + scnk * 8;
        uint4 val; val.x = lo.x; val.y = lo.y; val.z = hi.x; val.w = hi.y;
        *(uint4*)dst = val;
      }
      __syncthreads();
    }
    return;
  }

#pragma unroll
  for (int m = 0; m < 4; ++m) {
#pragma unroll
    for (int n = 0; n < 4; ++n) {
#pragma unroll
      for (int r = 0; r < 4; ++r) {
        const int row = m0 + wr * 64 + m * 16 + grp * 4 + r;
        const int col = n0 + wc * 64 + n * 16 + r16;
        const int cs = col & 1023;
        const float v = (acc[m][n][r] + bp[cs]) * sc;
        if (MODE == 3) {  // seg 0/1: head-major
          const int b = row >> 11, s = row & 2047, h = cs >> 6, d = cs & 63;
          bf16* base = (bf16*)Out + (size_t)seg * NQKV;
          base[((size_t)(b * NH + h) * S_LEN + s) * HD + d] = (bf16)v;
        } else {
          ((float*)Out)[(size_t)row * N + col] = v;
        }
      }
    }
  }
}

// ---------------- causal flash attention: single-chunk blocks, 3/CU ------------
// 1024 blocks x 4 waves; block = (bh, one 64-row q-chunk c), nt = c+1 tiles.
// Heavy-first dispatch (c=31 first across all XCDs/heads) + hardware backfill
// approximates LPT scheduling. 48KB ring -> 3 blocks/CU co-resident (12
// waves/CU vs round-8's 8): more TLP to hide the per-tile serial chain, which
// round-6/8 accounting showed is ~50% dead time at 2 waves/SIMD.
// Inner structure identical to round-8 (51.4us measured): wave (qh,kh) =
// q-half x key-half; 3-slot LDS ring, counted vmcnt(4) (T4), stage(kt+2) after
// barrier; XOR-swizzled staging (rule #21); swapped-operand MFMA; T13
// defer-max; split-K combine via LDS at chunk end.
__global__ __launch_bounds__(256, 3) void attn_fwd13(
    const bf16* __restrict__ Qh, const bf16* __restrict__ Kh,
    const bf16* __restrict__ Vt, bf16* __restrict__ AO) {
  __shared__ __align__(16) bf16 Kl[3][64 * 64];
  __shared__ __align__(16) bf16 Vl[3][64 * 64];

  const int tid = threadIdx.x;
  const int lane = tid & 63, w = tid >> 6;
  const int q31 = lane & 31, h = lane >> 5;
  const int qh = w >> 1, kh = w & 1;
  const int koff = kh << 5;

  // 1024 blocks: xcd = bid&7 (4 heads/XCD for K/V L2 residency);
  // within = bid>>3 (0..127): head = within&3, chunk slot = within>>2 (0..31),
  // c = 31 - slot -> heavy chunks dispatched first.
  const int bid = blockIdx.x;
  const int xcd = bid & 7;
  const int within = bid >> 3;
  const int bh = xcd * 4 + (within & 3);
  const int c = 31 - (within >> 2);

  const bf16* Qb = Qh + (size_t)bh * S_LEN * HD;
  const bf16* Kb = Kh + (size_t)bh * S_LEN * HD;
  const bf16* Vb = Vt + (size_t)bh * HD * S_LEN;

  // staging offsets: 8KB tile = 512 x 16B; 256 threads x 2 issues (K and V)
  int stK[2], stV[2], stL[2];
#pragma unroll
  for (int i = 0; i < 2; ++i) {
    const int lin = i * 256 + tid;       // 0..511
    const int row = lin >> 3;            // 0..63
    const int colb = (lin & 7) * 16;
    const int scol = colb ^ ((row & 7) << 4);
    stK[i] = row * HD + (scol >> 1);
    stV[i] = row * S_LEN + (scol >> 1);
    stL[i] = lin * 8;
  }
  const int swz = (q31 & 7) << 4;

#define STAGE(t, buf)                                                          \
  {                                                                            \
    const bf16* kb_ = Kb + (size_t)(t) * 64 * HD;                              \
    const bf16* vb_ = Vb + (t) * 64;                                           \
    _Pragma("unroll") for (int i = 0; i < 2; ++i) {                            \
      gload_lds16(kb_ + stK[i], &Kl[buf][stL[i]]);                             \
      gload_lds16(vb_ + stV[i], &Vl[buf][stL[i]]);                             \
    }                                                                          \
  }

  {
    const int q0 = c << 6;
    const int nt = c + 1;
    const int q0w = q0 + (qh << 5);
    const int qg = q0w + q31;
    const int nt_w = (w == 1) ? nt - 1 : nt;   // w1's key-half never reaches diag
    const bool maskw = (w == 0) || (w == 3);   // triangular waves

    bf16x8 qf[4];
#pragma unroll
    for (int ks = 0; ks < 4; ++ks)
      qf[ks] = *(const bf16x8*)&Qb[(size_t)qg * HD + ks * 16 + 8 * h];

    f32x16 acc0 = {}, acc1 = {};
    float m = -1e30f, l = 0.f;

    // prologue: tiles 0,1 into buffers 0,1
    STAGE(0, 0)
    if (nt > 1) STAGE(1, 1)

    int cur = 0;
    for (int kt = 0; kt < nt; ++kt) {
      // tile kt landed when only tile kt+1's 4 stage-instrs are outstanding
      if (kt + 1 < nt) asm volatile("s_waitcnt vmcnt(4)" ::: "memory");
      else             asm volatile("s_waitcnt vmcnt(0)" ::: "memory");
      __builtin_amdgcn_s_barrier();

      if (kt + 2 < nt) {
        int nxt = cur + 2; if (nxt >= 3) nxt -= 3;
        STAGE(kt + 2, nxt)
      }

      if (kt < nt_w) {
        const bf16* KlC = &Kl[cur][0];
        const bf16* VlC = &Vl[cur][0];

        // K A-frags: 32 keys at koff (row = koff+q31; (koff+q31)&7 == q31&7)
        bf16x8 kf[4];
#pragma unroll
        for (int ks = 0; ks < 4; ++ks) {
          const int cc = (32 * ks + 16 * h) ^ swz;
          kf[ks] = *(const bf16x8*)((const char*)KlC + (koff + q31) * 128 + cc);
        }

        // ---- QK^T (32q x 32k x 64d = 4 mfma) ----
        f32x16 p0 = {};
        __builtin_amdgcn_s_setprio(1);
#pragma unroll
        for (int ks = 0; ks < 4; ++ks)
          p0 = __builtin_amdgcn_mfma_f32_32x32x16_bf16(kf[ks], qf[ks], p0, 0, 0, 0);
        __builtin_amdgcn_s_setprio(0);

        // V A-frags (rows d, cols = wave's 32-key half)
        bf16x8 vf[4];
#pragma unroll
        for (int ks = 0; ks < 2; ++ks)
#pragma unroll
          for (int db = 0; db < 2; ++db) {
            const int cc = (64 * kh + 32 * ks + 16 * h) ^ swz;
            vf[ks * 2 + db] =
                *(const bf16x8*)((const char*)VlC + (db * 32 + q31) * 128 + cc);
          }

        // ---- causal mask (diag tile, triangular waves only) ----
        if (maskw && kt == nt - 1) {
#pragma unroll
          for (int r = 0; r < 16; ++r) {
            const int key = (kt << 6) + koff + (r & 3) + 8 * (r >> 2) + 4 * h;
            if (key > qg) p0[r] = -1e30f;
          }
        }
        // ---- tree max over 16 + cross-half shuffle ----
        float t_[16];
#pragma unroll
        for (int r = 0; r < 16; ++r) t_[r] = p0[r];
#pragma unroll
        for (int s = 8; s >= 1; s >>= 1)
#pragma unroll
          for (int r = 0; r < s; ++r) t_[r] = fmaxf(t_[r], t_[r + s]);
        const float pmax = fmaxf(t_[0], __shfl_xor(t_[0], 32));
        // ---- defer-max (T13) ----
        if (!__all(pmax - m <= 8.0f)) {
          const float mn = fmaxf(m, pmax);
          const float al = exp2f(m - mn);
          m = mn;
          l *= al;
#pragma unroll
          for (int r = 0; r < 16; ++r) { acc0[r] *= al; acc1[r] *= al; }
        }
        // ---- exp + tree sum ----
        float sv[16];
#pragma unroll
        for (int r = 0; r < 16; ++r) {
          p0[r] = exp2f(p0[r] - m);
          sv[r] = p0[r];
        }
#pragma unroll
        for (int s = 8; s >= 1; s >>= 1)
#pragma unroll
          for (int r = 0; r < s; ++r) sv[r] += sv[r + s];
        l += sv[0] + __shfl_xor(sv[0], 32);

        // ---- pack P -> 2 PV B-frags via permlane32_swap ----
        unsigned wv[8];
#pragma unroll
        for (int mm = 0; mm < 8; ++mm)
          wv[mm] = packbf(p0[2 * mm], p0[2 * mm + 1]);
        pl32swap(wv[0], wv[2]);
        pl32swap(wv[1], wv[3]);
        pl32swap(wv[4], wv[6]);
        pl32swap(wv[5], wv[7]);

        // ---- PV (2 k-steps x 2 d-halves) ----
        __builtin_amdgcn_s_setprio(1);
        {
          u32x4 pu0 = {wv[0], wv[1], wv[2], wv[3]};
          const bf16x8 pf0 = __builtin_bit_cast(bf16x8, pu0);
          acc0 = __builtin_amdgcn_mfma_f32_32x32x16_bf16(vf[0], pf0, acc0, 0, 0, 0);
          acc1 = __builtin_amdgcn_mfma_f32_32x32x16_bf16(vf[1], pf0, acc1, 0, 0, 0);
          u32x4 pu1 = {wv[4], wv[5], wv[6], wv[7]};
          const bf16x8 pf1 = __builtin_bit_cast(bf16x8, pu1);
          acc0 = __builtin_amdgcn_mfma_f32_32x32x16_bf16(vf[2], pf1, acc0, 0, 0, 0);
          acc1 = __builtin_amdgcn_mfma_f32_32x32x16_bf16(vf[3], pf1, acc1, 0, 0, 0);
        }
        __builtin_amdgcn_s_setprio(0);
      }

      ++cur; if (cur == 3) cur = 0;
    }

    // ---- split-K combine across key-half waves (scratch = Kl area) ----
    float* scr = (float*)&Kl[0][0];
    float* s = scr + (size_t)qh * (64 * 34) + lane * 34;
    __syncthreads();  // all reads of ring done; safe to reuse as scratch
    if (kh) {
#pragma unroll
      for (int r = 0; r < 16; ++r) { s[r] = acc0[r]; s[16 + r] = acc1[r]; }
      s[32] = m;
      s[33] = l;
    }
    __syncthreads();
    if (!kh) {
      const float m1 = s[32], l1 = s[33];
      const float mn = fmaxf(m, m1);
      const float a0 = exp2f(m - mn), a1 = exp2f(m1 - mn);
      const float linv = 1.0f / (a0 * l + a1 * l1);
      const int b = bh >> 4, hh = bh & 15;
      bf16* orow = AO + ((size_t)(b * S_LEN + qg)) * DM + hh * HD;
#pragma unroll
      for (int mm = 0; mm < 4; ++mm) {
        bf16x4 ov0, ov1;
#pragma unroll
        for (int t2 = 0; t2 < 4; ++t2) {
          ov0[t2] = (bf16)((a0 * acc0[4 * mm + t2] + a1 * s[4 * mm + t2]) * linv);
          ov1[t2] = (bf16)((a0 * acc1[4 * mm + t2] + a1 * s[16 + 4 * mm + t2]) * linv);
        }
        *(bf16x4*)&orow[8 * mm + 4 * h] = ov0;
        *(bf16x4*)&orow[32 + 8 * mm + 4 * h] = ov1;
      }
    }
  }
#undef STAGE
}

// ---------------- launch ----------------
extern "C" void kernel_launch(void* const* d_in, const int* in_sizes, int n_in,
                              void* d_out, int out_size, void* d_ws, size_t ws_size,
                              hipStream_t stream) {
  const float* q  = (const float*)d_in[0];
  const float* k  = (const float*)d_in[1];
  const float* v  = (const float*)d_in[2];
  const float* Wq = (const float*)d_in[3];
  const float* bq = (const float*)d_in[4];
  const float* Wk = (const float*)d_in[5];
  const float* bk = (const float*)d_in[6];
  const float* Wv = (const float*)d_in[7];
  const float* bv = (const float*)d_in[8];
  const float* Wo = (const float*)d_in[9];
  const float* bo = (const float*)d_in[10];

  const int NTOK = 2 * S_LEN;          // 4096

  bf16* qb  = (bf16*)d_ws;             // q,k,v bf16: 3 * NQKV (consecutive)
  bf16* Wqb = qb + 3 * (size_t)NQKV;   // Wq,Wk,Wv,Wo bf16: 4 * NW (consecutive)
  bf16* Wob = Wqb + 3 * (size_t)NW;
  bf16* Qh  = Wqb + 4 * (size_t)NW;    // Qh,Kh,Vt bf16: 3 * NQKV (consecutive)
  bf16* Kh  = Qh + (size_t)NQKV;
  bf16* Vt  = Kh + (size_t)NQKV;
  bf16* AO  = Vt + (size_t)NQKV;

  const int cvt_blocks = (3 * NQKV + 4 * NW) / 8 / 256;
  cvt_all<<<cvt_blocks, 256, 0, stream>>>(q, k, v, Wq, Wk, Wv, Wo, qb);

  // fused QKV projection: M=4096, N=3072, K=1024
  gemm_bt<3><<<dim3(3 * DM / 128, NTOK / 128), 256, 0, stream>>>(
      qb, Wqb, bq, bk, bv, Qh, NTOK, 3 * DM, DM, QK_SCALE);

  // attention: 1024 single-chunk blocks x 256 threads, heavy-first, 3/CU
  attn_fwd13<<<dim3(1024), 256, 0, stream>>>(Qh, Kh, Vt, AO);

  // output projection -> fp32 d_out
  gemm_bt<2><<<dim3(DM / 128, NTOK / 128), 256, 0, stream>>>(
      AO, Wob, bo, bo, bo, d_out, NTOK, DM, DM, 1.0f);
}